// Round 12
// baseline (198.199 us; speedup 1.0000x reference)
//
#include <hip/hip_runtime.h>
#include <math.h>

#define NA 360
#define NP 512
#define NB 16
#define IMG 512
#define PS 514               // p' in [0,513]; point p' holds taps (s[p'-1], s[p'])
#define ACH 8                // angles per LDS chunk
#define NCH (NA / ACH)       // 45 chunks
#define NPT 32               // LDS points per angle (span <= 25 incl. margins)
#define PFD 4                // global-path prefetch distance (angles)

typedef unsigned int uint32;
typedef __fp16 half2 __attribute__((ext_vector_type(2)));   // builtin V2h type

static __device__ __forceinline__ half2 u2h(uint32 u) {
    union { uint32 u; half2 h; } v; v.u = u; return v.h;
}
static __device__ __forceinline__ uint32 pk(float a, float b) {
    union { half2 h; uint32 u; } v;
    v.h = __builtin_amdgcn_cvt_pkrtz(a, b);
    return v.u;
}

#if __has_builtin(__builtin_amdgcn_fdot2)
static __device__ __forceinline__ float dot2(half2 w, half2 v, float acc) {
    return __builtin_amdgcn_fdot2(w, v, acc, false);
}
#else
static __device__ __forceinline__ float dot2(half2 w, half2 v, float acc) {
    return fmaf((float)w.x, (float)v.x, fmaf((float)w.y, (float)v.y, acc));
}
#endif

// tab[a] = {c'=cos/dp, s'=sin/dp, off=-pos0/dp, (|c'|+|s'|)*7.5 (block half-span)}
static __device__ __forceinline__ void write_tab(const float* thetas,
                                                 const float* positions,
                                                 float4* tab, int a) {
    double th = (double)thetas[a];
    double p0 = (double)positions[0];
    double dp = (double)positions[1] - p0;
    double c = cos(th) / dp, s = sin(th) / dp;
    tab[a] = make_float4((float)c, (float)s, (float)(-p0 / dp),
                         (float)((fabs(c) + fabs(s)) * 7.5));
}

// Staging: [b][a][p] f32 -> 4 planes, plane k: [a][p'] uint4 = f16 tap-pairs
// for batches 4k..4k+3. One thread per (plane, point) for TLP.
__global__ void stage(const float* __restrict__ sino,
                      const float* __restrict__ thetas,
                      const float* __restrict__ positions,
                      float4* __restrict__ tab,
                      uint4* __restrict__ st) {
    if (blockIdx.x == gridDim.x - 1) {
        int a = threadIdx.x;
        if (a < NA) write_tab(thetas, positions, tab, a);
        int a2 = threadIdx.x + 256;
        if (a2 < NA) write_tab(thetas, positions, tab, a2);
        return;
    }
    int idx = blockIdx.x * 256 + threadIdx.x;   // idx = (k*NA + a)*PS + p'
    if (idx >= 4 * NA * PS) return;
    const int k   = idx / (NA * PS);
    const int rem = idx - k * (NA * PS);
    const int a   = rem / PS;
    const int pp  = rem - a * PS;
    const int p0  = pp - 1;
    uint32 r[4];
#pragma unroll
    for (int i = 0; i < 4; ++i) {
        const float* row = sino + ((size_t)(4 * k + i) * NA + a) * NP;
        float f0 = (p0 >= 0 && p0 < NP) ? row[p0] : 0.0f;
        float f1 = (pp < NP) ? row[pp] : 0.0f;
        r[i] = pk(f0, f1);
    }
    st[idx] = make_uint4(r[0], r[1], r[2], r[3]);
}

// Window start with 1-point lower margin against fp rounding (round-8 lesson).
static __device__ __forceinline__ int pmin_of(float tc, float tw) {
    float fmn = fminf(fmaxf(tc - tw, -1.0f), 512.0f);
    return min(max((int)floorf(fmn) - 1, 0), PS - NPT);
}

// Hybrid: planes 0-1 via LDS window DMA (2 ds_read_b128/angle); planes 2-3
// via direct global gather with DISTANCE-4 named-register prefetch (round-11
// lesson: distance-2 left L3-latency stalls uncovered -> paths serialized).
__launch_bounds__(256)
__global__ void backproject(const uint4* __restrict__ st,
                            const float4* __restrict__ tab,
                            float* __restrict__ out) {
    __shared__ uint4 buf[2][ACH * 2 * NPT];     // 2 x 8 KB, [al][q][pt]
    __shared__ int pm_lds[NA];                  // 1.44 KB
    const int tid = threadIdx.y * 16 + threadIdx.x;
    const int x = blockIdx.x * 16 + threadIdx.x;
    const int y = blockIdx.y * 16 + threadIdx.y;
    const float xs = (float)x - 255.5f;
    const float ys = (float)y - 255.5f;
    const float xc = (float)(blockIdx.x * 16) + 7.5f - 255.5f;   // block center
    const float yc = (float)(blockIdx.y * 16) + 7.5f - 255.5f;

    // ---- prologue: block-uniform pmin for every angle ----
    for (int a = tid; a < NA; a += 256) {
        const float4 t = tab[a];
        float tc = fmaf(xc, t.x, fmaf(yc, t.y, t.z));
        pm_lds[a] = pmin_of(tc, t.w);
    }
    __syncthreads();

    float acc[NB];
#pragma unroll
    for (int b = 0; b < NB; ++b) acc[b] = 0.0f;

    const uint4* __restrict__ pl2 = st + (size_t)2 * (NA * PS);
    const uint4* __restrict__ pl3 = st + (size_t)3 * (NA * PS);

    // DMA one chunk's 2-plane window into buf[bsel] (round-10/11 pattern).
    auto issue_dma = [&](int ch, int bsel) {
#pragma unroll
        for (int j = 0; j < 2; ++j) {
            const int s  = tid + 256 * j;
            const int al = s >> 6, q = (s >> 5) & 1, pt = s & 31;
            const int a  = ch * ACH + al;
            const int pm = pm_lds[a];
            const uint4* gp = &st[(size_t)q * (NA * PS) + (size_t)a * PS + pm + pt];
            __builtin_amdgcn_global_load_lds(
                (__attribute__((address_space(1))) const void*)gp,
                (__attribute__((address_space(3))) void*)&buf[bsel][s], 16, 0, 0);
        }
    };

    auto fidx_of = [&](int a) -> float {
        const float4 t = tab[a];
        float f = fmaf(xs, t.x, fmaf(ys, t.y, t.z));
        return fminf(fmaxf(f, -1.0f), 512.0f);
    };

    // prologue: prefetch angles 0..3 for the global path
    uint4 p2[PFD], p3[PFD];
#pragma unroll
    for (int j = 0; j < PFD; ++j) {
        const int gi = j * PS + ((int)floorf(fidx_of(j)) + 1);
        p2[j] = pl2[gi];
        p3[j] = pl3[gi];
    }

    issue_dma(0, 0);

#pragma unroll 1
    for (int ch = 0; ch < NCH; ++ch) {
        __syncthreads();                        // drains vmcnt: buf[ch&1] ready
        if (ch + 1 < NCH) issue_dma(ch + 1, (ch + 1) & 1);

        const int a0 = ch * ACH;
        const uint4* b = buf[ch & 1];
#pragma unroll
        for (int al = 0; al < ACH; ++al) {      // full unroll: slots stay named
            const int a = a0 + al;
            const int slot = al & 3;
            const float fidx = fidx_of(a);
            const float fl = floorf(fidx);
            const float w = fidx - fl;
            const half2 wp = u2h(pk(1.0f - w, w));
            const int idx = ((int)fl + 1) - pm_lds[a];
            const uint4 d0 = b[al * 64 + idx];          // plane 0 (LDS)
            const uint4 d1 = b[al * 64 + 32 + idx];     // plane 1 (LDS)
            const uint4 g2 = p2[slot];                  // plane 2 (prefetched)
            const uint4 g3 = p3[slot];                  // plane 3 (prefetched)
            acc[0]  = dot2(wp, u2h(d0.x), acc[0]);
            acc[1]  = dot2(wp, u2h(d0.y), acc[1]);
            acc[2]  = dot2(wp, u2h(d0.z), acc[2]);
            acc[3]  = dot2(wp, u2h(d0.w), acc[3]);
            acc[4]  = dot2(wp, u2h(d1.x), acc[4]);
            acc[5]  = dot2(wp, u2h(d1.y), acc[5]);
            acc[6]  = dot2(wp, u2h(d1.z), acc[6]);
            acc[7]  = dot2(wp, u2h(d1.w), acc[7]);
            acc[8]  = dot2(wp, u2h(g2.x), acc[8]);
            acc[9]  = dot2(wp, u2h(g2.y), acc[9]);
            acc[10] = dot2(wp, u2h(g2.z), acc[10]);
            acc[11] = dot2(wp, u2h(g2.w), acc[11]);
            acc[12] = dot2(wp, u2h(g3.x), acc[12]);
            acc[13] = dot2(wp, u2h(g3.y), acc[13]);
            acc[14] = dot2(wp, u2h(g3.z), acc[14]);
            acc[15] = dot2(wp, u2h(g3.w), acc[15]);
            // refill slot with angle a+4 (clamped tail loads never consumed)
            const int an = min(a + PFD, NA - 1);
            const int gi = an * PS + ((int)floorf(fidx_of(an)) + 1);
            p2[slot] = pl2[gi];
            p3[slot] = pl3[gi];
        }
    }

    const size_t pix = (size_t)y * IMG + x;
#pragma unroll
    for (int b = 0; b < NB; ++b)
        out[(size_t)b * (IMG * IMG) + pix] = acc[b];
}

extern "C" void kernel_launch(void* const* d_in, const int* in_sizes, int n_in,
                              void* d_out, int out_size, void* d_ws, size_t ws_size,
                              hipStream_t stream) {
    const float* sino      = (const float*)d_in[0];
    const float* thetas    = (const float*)d_in[1];
    const float* positions = (const float*)d_in[2];
    float* out = (float*)d_out;

    float4* tab = (float4*)d_ws;                     // 360 * 16 B
    uint4*  st  = (uint4*)((char*)d_ws + 8192);      // 4 planes * 2.96 MB = 11.84 MB

    const int nb = (4 * NA * PS + 255) / 256 + 1;    // +1 block computes tab
    stage<<<dim3(nb), dim3(256), 0, stream>>>(sino, thetas, positions, tab, st);
    backproject<<<dim3(IMG / 16, IMG / 16), dim3(16, 16), 0, stream>>>(st, tab, out);
}

// Round 13
// 167.185 us; speedup vs baseline: 1.1855x; 1.1855x over previous
//
#include <hip/hip_runtime.h>
#include <math.h>

#define NA 360
#define NP 512
#define NB 16
#define IMG 512
#define PS 514               // p' in [0,513]; point p' holds taps (s[p'-1], s[p'])
#define ACH 8                // angles per LDS chunk
#define NCH (NA / ACH)       // 45 chunks
#define NPT 32               // LDS points per angle (span <= 25 incl. margins)

typedef unsigned int uint32;
typedef __fp16 half2 __attribute__((ext_vector_type(2)));   // builtin V2h type

static __device__ __forceinline__ half2 u2h(uint32 u) {
    union { uint32 u; half2 h; } v; v.u = u; return v.h;
}
static __device__ __forceinline__ uint32 pk(float a, float b) {
    union { half2 h; uint32 u; } v;
    v.h = __builtin_amdgcn_cvt_pkrtz(a, b);
    return v.u;
}

#if __has_builtin(__builtin_amdgcn_fdot2)
static __device__ __forceinline__ float dot2(half2 w, half2 v, float acc) {
    return __builtin_amdgcn_fdot2(w, v, acc, false);
}
#else
static __device__ __forceinline__ float dot2(half2 w, half2 v, float acc) {
    return fmaf((float)w.x, (float)v.x, fmaf((float)w.y, (float)v.y, acc));
}
#endif

// tab[a] = {c'=cos/dp, s'=sin/dp, off=-pos0/dp, (|c'|+|s'|)*7.5 (block half-span)}
static __device__ __forceinline__ void write_tab(const float* thetas,
                                                 const float* positions,
                                                 float4* tab, int a) {
    double th = (double)thetas[a];
    double p0 = (double)positions[0];
    double dp = (double)positions[1] - p0;
    double c = cos(th) / dp, s = sin(th) / dp;
    tab[a] = make_float4((float)c, (float)s, (float)(-p0 / dp),
                         (float)((fabs(c) + fabs(s)) * 7.5));
}

// Staging: [b][a][p] f32 -> 4 planes, plane k: [a][p'] uint4 = f16 tap-pairs
// for batches 4k..4k+3. One thread per (plane, point) for TLP (round-11 stage).
__global__ void stage(const float* __restrict__ sino,
                      const float* __restrict__ thetas,
                      const float* __restrict__ positions,
                      float4* __restrict__ tab,
                      uint4* __restrict__ st) {
    if (blockIdx.x == gridDim.x - 1) {
        int a = threadIdx.x;
        if (a < NA) write_tab(thetas, positions, tab, a);
        int a2 = threadIdx.x + 256;
        if (a2 < NA) write_tab(thetas, positions, tab, a2);
        return;
    }
    int idx = blockIdx.x * 256 + threadIdx.x;   // idx = (k*NA + a)*PS + p'
    if (idx >= 4 * NA * PS) return;
    const int k   = idx / (NA * PS);
    const int rem = idx - k * (NA * PS);
    const int a   = rem / PS;
    const int pp  = rem - a * PS;
    const int p0  = pp - 1;
    uint32 r[4];
#pragma unroll
    for (int i = 0; i < 4; ++i) {
        const float* row = sino + ((size_t)(4 * k + i) * NA + a) * NP;
        float f0 = (p0 >= 0 && p0 < NP) ? row[p0] : 0.0f;
        float f1 = (pp < NP) ? row[pp] : 0.0f;
        r[i] = pk(f0, f1);
    }
    st[idx] = make_uint4(r[0], r[1], r[2], r[3]);
}

// Window start with 1-point lower margin against fp rounding (round-8 lesson).
static __device__ __forceinline__ int pmin_of(float tc, float tw) {
    float fmn = fminf(fmaxf(tc - tw, -1.0f), 512.0f);
    return min(max((int)floorf(fmn) - 1, 0), PS - NPT);
}

// Round-10 pure-LDS backproject (proven 113.5 us = 98% of the LDS-pipe
// roofline: 6.04 GB of gathers at 85 B/cyc/CU = 116 us; conflicts 0).
// Hybrid TA/LDS splits tried twice (rounds 11/12): +32 us both times —
// VALU becomes critical and pipes serialize at issue. Do not revisit.
// DMA straight into LDS via global_load_lds (no VGPR staging -> no spill;
// round-9 lesson: 474 MB scratch writes when regs crossed the barrier).
__launch_bounds__(256)
__global__ void backproject(const uint4* __restrict__ st,
                            const float4* __restrict__ tab,
                            float* __restrict__ out) {
    __shared__ uint4 buf[2][ACH * 4 * NPT];     // 2 x 16 KB, [al][q][pt]
    __shared__ int pm_lds[NA];                  // 1.44 KB
    const int tid = threadIdx.y * 16 + threadIdx.x;
    const int x = blockIdx.x * 16 + threadIdx.x;
    const int y = blockIdx.y * 16 + threadIdx.y;
    const float xs = (float)x - 255.5f;
    const float ys = (float)y - 255.5f;
    const float xc = (float)(blockIdx.x * 16) + 7.5f - 255.5f;   // block center
    const float yc = (float)(blockIdx.y * 16) + 7.5f - 255.5f;

    // ---- prologue: block-uniform pmin for every angle ----
    for (int a = tid; a < NA; a += 256) {
        const float4 t = tab[a];
        float tc = fmaf(xc, t.x, fmaf(yc, t.y, t.z));
        pm_lds[a] = pmin_of(tc, t.w);
    }
    __syncthreads();

    float acc[NB];
#pragma unroll
    for (int b = 0; b < NB; ++b) acc[b] = 0.0f;

    const int qld = (tid >> 5) & 3;             // this thread's load plane
    const int ptl = tid & 31;                   // this thread's load point
    const int hl  = tid >> 7;                   // odd/even angle for loads

    // DMA one chunk's window into buf[bsel]: load j covers angle 2j+hl.
    // LDS slot tid+256j -> per-wave base is lane-contiguous (lane x 16 B).
    auto issue = [&](int ch, int bsel) {
#pragma unroll
        for (int j = 0; j < 4; ++j) {
            const int a = ch * ACH + 2 * j + hl;
            const int pm = pm_lds[a];
            const uint4* gp = &st[(size_t)qld * (NA * PS) + (size_t)a * PS + pm + ptl];
            uint4* lp = &buf[bsel][tid + 256 * j];
            __builtin_amdgcn_global_load_lds(
                (__attribute__((address_space(1))) const void*)gp,
                (__attribute__((address_space(3))) void*)lp, 16, 0, 0);
        }
    };

    issue(0, 0);

#pragma unroll 1
    for (int ch = 0; ch < NCH; ++ch) {
        __syncthreads();                        // drains vmcnt: buf[ch&1] ready
        if (ch + 1 < NCH) issue(ch + 1, (ch + 1) & 1);

        const int a0 = ch * ACH;
        const uint4* b = buf[ch & 1];
#pragma unroll
        for (int al = 0; al < ACH; ++al) {
            const float4 t = tab[a0 + al];      // uniform -> s_load
            float fidx = fmaf(xs, t.x, fmaf(ys, t.y, t.z));
            fidx = fminf(fmaxf(fidx, -1.0f), 512.0f);
            const float fl = floorf(fidx);
            const float w = fidx - fl;
            const half2 wp = u2h(pk(1.0f - w, w));
            const int idx = ((int)fl + 1) - pm_lds[a0 + al];   // [0, 31]
            const uint4 d0 = b[al * 128 + 0 * 32 + idx];
            const uint4 d1 = b[al * 128 + 1 * 32 + idx];
            const uint4 d2 = b[al * 128 + 2 * 32 + idx];
            const uint4 d3 = b[al * 128 + 3 * 32 + idx];
            acc[0]  = dot2(wp, u2h(d0.x), acc[0]);
            acc[1]  = dot2(wp, u2h(d0.y), acc[1]);
            acc[2]  = dot2(wp, u2h(d0.z), acc[2]);
            acc[3]  = dot2(wp, u2h(d0.w), acc[3]);
            acc[4]  = dot2(wp, u2h(d1.x), acc[4]);
            acc[5]  = dot2(wp, u2h(d1.y), acc[5]);
            acc[6]  = dot2(wp, u2h(d1.z), acc[6]);
            acc[7]  = dot2(wp, u2h(d1.w), acc[7]);
            acc[8]  = dot2(wp, u2h(d2.x), acc[8]);
            acc[9]  = dot2(wp, u2h(d2.y), acc[9]);
            acc[10] = dot2(wp, u2h(d2.z), acc[10]);
            acc[11] = dot2(wp, u2h(d2.w), acc[11]);
            acc[12] = dot2(wp, u2h(d3.x), acc[12]);
            acc[13] = dot2(wp, u2h(d3.y), acc[13]);
            acc[14] = dot2(wp, u2h(d3.z), acc[14]);
            acc[15] = dot2(wp, u2h(d3.w), acc[15]);
        }
    }

    const size_t pix = (size_t)y * IMG + x;
#pragma unroll
    for (int b = 0; b < NB; ++b)
        out[(size_t)b * (IMG * IMG) + pix] = acc[b];
}

extern "C" void kernel_launch(void* const* d_in, const int* in_sizes, int n_in,
                              void* d_out, int out_size, void* d_ws, size_t ws_size,
                              hipStream_t stream) {
    const float* sino      = (const float*)d_in[0];
    const float* thetas    = (const float*)d_in[1];
    const float* positions = (const float*)d_in[2];
    float* out = (float*)d_out;

    float4* tab = (float4*)d_ws;                     // 360 * 16 B
    uint4*  st  = (uint4*)((char*)d_ws + 8192);      // 4 planes * 2.96 MB = 11.84 MB

    const int nb = (4 * NA * PS + 255) / 256 + 1;    // +1 block computes tab
    stage<<<dim3(nb), dim3(256), 0, stream>>>(sino, thetas, positions, tab, st);
    backproject<<<dim3(IMG / 16, IMG / 16), dim3(16, 16), 0, stream>>>(st, tab, out);
}